// Round 3
// baseline (119.802 us; speedup 1.0000x reference)
//
#include <hip/hip_runtime.h>

#define M_ROWS 1024
#define DIM 512
#define NB 1024              // row bytes = DIM*2
#define N_TOT 7168           // M + 2*M*C
#define TEXT_OFF 1024
#define SHUF_OFF 4096
#define INV_T (1.0f/0.07f)
#define MARGIN_V 0.2f
#define TILES 56             // N_TOT / 128
#define NBLK 1596            // TILES*(TILES+1)/2 upper-triangular tiles

typedef __attribute__((ext_vector_type(8))) short bf16x8;
typedef __attribute__((ext_vector_type(4))) float f32x4;

typedef const __attribute__((address_space(1))) unsigned int gas_uint;
typedef __attribute__((address_space(3))) unsigned int las_uint;

__device__ __forceinline__ void gload16(const void* g, void* l) {
  __builtin_amdgcn_global_load_lds((gas_uint*)g, (las_uint*)l, 16, 0, 0);
}

__device__ __forceinline__ ushort f2bf(float f) {
  unsigned u = __float_as_uint(f);
  u += 0x7fffu + ((u >> 16) & 1u);   // RTNE
  return (ushort)(u >> 16);
}

// ------- Kernel 1: normalize + cast bf16 + build ids + zero accumulators -------
__global__ __launch_bounds__(256) void k_normalize(
    const float* __restrict__ motion, const float* __restrict__ text,
    const float* __restrict__ shuf, const int* __restrict__ mids,
    ushort* __restrict__ emb, int* __restrict__ ids, float* __restrict__ accs) {
  // fused zeroing of denom/possum/margsum: 3*7168 floats = 5376 float4 = 21 blocks x 256
  if (blockIdx.x < 21) {
    float4 z = {0.f, 0.f, 0.f, 0.f};
    ((float4*)accs)[blockIdx.x * 256 + threadIdx.x] = z;
  }
  int wave = threadIdx.x >> 6;
  int lane = threadIdx.x & 63;
  int row = blockIdx.x * 4 + wave;
  if (row >= N_TOT) return;
  const float* src;
  int id;
  if (row < TEXT_OFF) { src = motion + (size_t)row * DIM; id = mids[row]; }
  else if (row < SHUF_OFF) { int r = row - TEXT_OFF; src = text + (size_t)r * DIM; id = mids[r / 3]; }
  else { int r = row - SHUF_OFF; src = shuf + (size_t)r * DIM; id = mids[r / 3] + 100000; }

  float4 a = ((const float4*)src)[lane * 2];
  float4 b = ((const float4*)src)[lane * 2 + 1];
  float v0 = a.x + 1e-8f, v1 = a.y + 1e-8f, v2 = a.z + 1e-8f, v3 = a.w + 1e-8f;
  float v4 = b.x + 1e-8f, v5 = b.y + 1e-8f, v6 = b.z + 1e-8f, v7 = b.w + 1e-8f;
  float ss = v0*v0 + v1*v1 + v2*v2 + v3*v3 + v4*v4 + v5*v5 + v6*v6 + v7*v7;
  #pragma unroll
  for (int m = 1; m < 64; m <<= 1) ss += __shfl_xor(ss, m);
  float inv = 1.0f / fmaxf(sqrtf(ss), 1e-12f);

  uint w0 = (uint)f2bf(v0 * inv) | ((uint)f2bf(v1 * inv) << 16);
  uint w1 = (uint)f2bf(v2 * inv) | ((uint)f2bf(v3 * inv) << 16);
  uint w2 = (uint)f2bf(v4 * inv) | ((uint)f2bf(v5 * inv) << 16);
  uint w3 = (uint)f2bf(v6 * inv) | ((uint)f2bf(v7 * inv) << 16);
  uint4 pk; pk.x = w0; pk.y = w1; pk.z = w2; pk.w = w3;
  *((uint4*)(emb + (size_t)row * DIM + lane * 8)) = pk;
  if (lane == 0) ids[row] = id;
}

// -------- Kernel 2: symmetric fused A*A^T + masked row/col reductions --------
// Upper-triangular 128x128 tiles; triple-buffered LDS, 2-ahead prefetch with
// counted vmcnt(4); XCD-chunked bid swizzle for L2 locality.
__global__ __launch_bounds__(256, 3) void k_gemm_loss(
    const ushort* __restrict__ emb, const int* __restrict__ ids,
    float* __restrict__ denom, float* __restrict__ possum, float* __restrict__ margsum) {
  __shared__ ushort As[3][4096];   // [buf][128 rows x 32 bf16], 8 KB each
  __shared__ ushort Bs[3][4096];
  __shared__ int rid[128];
  __shared__ int cid[128];

  // bijective XCD-chunked swizzle (m204): nwg=1596, q=199, r=4
  int orig = blockIdx.x;
  int xcd = orig & 7;
  int idx = orig >> 3;
  int bid = (xcd < 4 ? xcd * 200 : 800 + (xcd - 4) * 199) + idx;

  // triangular tile decode: bid -> (x, y), x <= y
  int x = 0;
  while (bid >= TILES - x) { bid -= TILES - x; x++; }
  int y = x + bid;
  bool diag = (x == y);
  int brow = x * 128, bcol = y * 128;

  int t = threadIdx.x;
  int lane = t & 63;
  int wave = t >> 6;

  if (t < 128) rid[t] = ids[brow + t];
  else cid[t - 128] = ids[bcol + (t - 128)];

  // staging geometry: per K-step each wave issues 4 gload16 calls of 1024 B
  int srow0 = wave * 16 + (lane >> 2);        // rows 0..63
  int srow1 = 64 + wave * 16 + (lane >> 2);   // rows 64..127
  int scolb = (lane & 3) * 16;                // byte offset within 64 B K-chunk
  const char* gA = (const char*)emb + (size_t)brow * NB;
  const char* gB = (const char*)emb + (size_t)bcol * NB;

  int wrow = (wave >> 1) * 64;
  int wcol = (wave & 1) * 64;
  int fr = lane & 15;
  int fc = (lane >> 4) * 8;

  f32x4 acc[4][4];
  #pragma unroll
  for (int m = 0; m < 4; m++)
    #pragma unroll
    for (int n = 0; n < 4; n++)
      acc[m][n] = (f32x4){0.f, 0.f, 0.f, 0.f};

#define STAGE(T) do { \
    const int _b = (T) % 3; const int _kb = (T) * 64; \
    gload16(gA + (size_t)srow0 * NB + _kb + scolb, &As[_b][wave * 512]); \
    gload16(gA + (size_t)srow1 * NB + _kb + scolb, &As[_b][2048 + wave * 512]); \
    gload16(gB + (size_t)srow0 * NB + _kb + scolb, &Bs[_b][wave * 512]); \
    gload16(gB + (size_t)srow1 * NB + _kb + scolb, &Bs[_b][2048 + wave * 512]); \
  } while (0)

#define COMPUTE(T) do { \
    const int _b = (T) % 3; \
    bf16x8 aF[4], bF[4]; \
    _Pragma("unroll") \
    for (int m = 0; m < 4; m++) \
      aF[m] = *(const bf16x8*)(&As[_b][(wrow + m * 16 + fr) * 32 + fc]); \
    _Pragma("unroll") \
    for (int n = 0; n < 4; n++) \
      bF[n] = *(const bf16x8*)(&Bs[_b][(wcol + n * 16 + fr) * 32 + fc]); \
    _Pragma("unroll") \
    for (int m = 0; m < 4; m++) \
      _Pragma("unroll") \
      for (int n = 0; n < 4; n++) \
        acc[m][n] = __builtin_amdgcn_mfma_f32_16x16x32_bf16(aF[m], bF[n], acc[m][n], 0, 0, 0); \
  } while (0)

  STAGE(0);
  STAGE(1);
  asm volatile("s_waitcnt vmcnt(4)" ::: "memory");   // t=0's 4 loads done
  __builtin_amdgcn_s_barrier();
  __builtin_amdgcn_sched_barrier(0);

  #pragma unroll
  for (int tt = 0; tt < 16; tt++) {
    if (tt + 2 < 16) STAGE(tt + 2);
    COMPUTE(tt);
    if (tt < 15) {
      if (tt + 2 < 16) {
        asm volatile("s_waitcnt vmcnt(4)" ::: "memory");   // (tt+1)'s loads done, (tt+2)'s in flight
      } else {
        asm volatile("s_waitcnt vmcnt(0)" ::: "memory");
      }
      __builtin_amdgcn_s_barrier();
      __builtin_amdgcn_sched_barrier(0);
    }
  }
#undef STAGE
#undef COMPUTE

  // Epilogue: per-element masks + row partials (i) and column partials (j).
  int cgrp = lane >> 4;
  int cl = lane & 15;
  float cd[4], cp[4], cm[4];
  #pragma unroll
  for (int n = 0; n < 4; n++) { cd[n] = 0.f; cp[n] = 0.f; cm[n] = 0.f; }

  #pragma unroll
  for (int m = 0; m < 4; m++) {
    #pragma unroll
    for (int r = 0; r < 4; r++) {
      int row_l = wrow + m * 16 + cgrp * 4 + r;
      int i = brow + row_l;
      int idi = rid[row_l];
      float dsum = 0.f, psum = 0.f, msum = 0.f;
      #pragma unroll
      for (int n = 0; n < 4; n++) {
        int col_l = wcol + n * 16 + cl;
        int j = bcol + col_l;
        float sim = acc[m][n][r] * INV_T;
        bool live = (!diag) || (i != j);
        if (live) {
          float e = __expf(sim);
          float hinge = fmaxf(sim + MARGIN_V, 0.f);
          bool same = (idi == cid[col_l]);
          float ps = same ? sim : 0.f;
          float ms = same ? 0.f : hinge;
          dsum += e; psum += ps; msum += ms;
          if (!diag) { cd[n] += e; cp[n] += ps; cm[n] += ms; }
        }
      }
      #pragma unroll
      for (int s = 1; s < 16; s <<= 1) {
        dsum += __shfl_xor(dsum, s);
        psum += __shfl_xor(psum, s);
        msum += __shfl_xor(msum, s);
      }
      if (cl == 0) {
        atomicAdd(&denom[i], dsum);
        atomicAdd(&possum[i], psum);
        atomicAdd(&margsum[i], msum);
      }
    }
  }

  if (!diag) {
    #pragma unroll
    for (int n = 0; n < 4; n++) {
      float d = cd[n], p = cp[n], mm = cm[n];
      d += __shfl_xor(d, 16); d += __shfl_xor(d, 32);
      p += __shfl_xor(p, 16); p += __shfl_xor(p, 32);
      mm += __shfl_xor(mm, 16); mm += __shfl_xor(mm, 32);
      if (lane < 16) {
        int j = bcol + wcol + n * 16 + cl;
        atomicAdd(&denom[j], d);
        atomicAdd(&possum[j], p);
        atomicAdd(&margsum[j], mm);
      }
    }
  }
}

// ---------------- Kernel 3: finalize ----------------
__global__ __launch_bounds__(256) void k_finalize(
    const int* __restrict__ mids, const float* __restrict__ denom,
    const float* __restrict__ possum, const float* __restrict__ margsum,
    float* __restrict__ out) {
  __shared__ int hist[256];
  __shared__ double red[256];
  __shared__ int redc[256];
  int t = threadIdx.x;
  hist[t] = 0;
  __syncthreads();
  for (int i = t; i < M_ROWS; i += 256) atomicAdd(&hist[mids[i]], 1);
  __syncthreads();

  double tot = 0.0;
  int cnt = 0;
  for (int i = t; i < N_TOT; i += 256) {
    int v; bool shuf = false;
    if (i < TEXT_OFF) v = mids[i];
    else if (i < SHUF_OFF) v = mids[(i - TEXT_OFF) / 3];
    else { v = mids[(i - SHUF_OFF) / 3]; shuf = true; }
    int c = hist[v];
    int npos = shuf ? (3 * c - 1) : (4 * c - 1);
    int nneg = N_TOT - 1 - npos;
    if (npos > 0 && nneg > 0) {
      float infonce = logf(denom[i]) - possum[i] / (float)(npos > 1 ? npos : 1);
      float marg = margsum[i] / (float)(nneg > 1 ? nneg : 1);
      tot += (double)(infonce + marg);
      cnt++;
    }
  }
  red[t] = tot; redc[t] = cnt;
  __syncthreads();
  for (int s = 128; s > 0; s >>= 1) {
    if (t < s) { red[t] += red[t + s]; redc[t] += redc[t + s]; }
    __syncthreads();
  }
  if (t == 0) {
    out[0] = (redc[0] > 0) ? (float)(red[0] / (double)redc[0]) : 0.f;
  }
}

// ---------------- Launch ----------------
extern "C" void kernel_launch(void* const* d_in, const int* in_sizes, int n_in,
                              void* d_out, int out_size, void* d_ws, size_t ws_size,
                              hipStream_t stream) {
  const float* motion = (const float*)d_in[0];
  const float* text   = (const float*)d_in[1];
  const float* shuf   = (const float*)d_in[2];
  const int*   mids   = (const int*)d_in[3];

  char* ws = (char*)d_ws;
  ushort* emb = (ushort*)ws;                                  // N*D bf16 = 7,340,032 B
  int* ids    = (int*)(ws + (size_t)N_TOT * DIM * 2);         // N*4
  float* denom = (float*)(ws + (size_t)N_TOT * DIM * 2 + (size_t)N_TOT * 4);
  float* possum  = denom + N_TOT;
  float* margsum = denom + 2 * N_TOT;

  k_normalize<<<N_TOT / 4, 256, 0, stream>>>(motion, text, shuf, mids, emb, ids, denom);
  k_gemm_loss<<<NBLK, 256, 0, stream>>>(emb, ids, denom, possum, margsum);
  k_finalize<<<1, 256, 0, stream>>>(mids, denom, possum, margsum, (float*)d_out);
}

// Round 4
// 115.743 us; speedup vs baseline: 1.0351x; 1.0351x over previous
//
#include <hip/hip_runtime.h>

#define M_ROWS 1024
#define DIM 512
#define NB 1024              // row bytes = DIM*2
#define N_TOT 7168           // M + 2*M*C
#define TEXT_OFF 1024
#define SHUF_OFF 4096
#define INV_T (1.0f/0.07f)
#define MARGIN_V 0.2f
#define TILES2 28            // N_TOT / 256
#define NBLK2 406            // 28*29/2 upper-triangular 256^2 tiles

typedef __attribute__((ext_vector_type(8))) short bf16x8;
typedef __attribute__((ext_vector_type(4))) float f32x4;

typedef const __attribute__((address_space(1))) unsigned int gas_uint;
typedef __attribute__((address_space(3))) unsigned int las_uint;

__device__ __forceinline__ void gload16(const void* g, void* l) {
  __builtin_amdgcn_global_load_lds((gas_uint*)g, (las_uint*)l, 16, 0, 0);
}

__device__ __forceinline__ ushort f2bf(float f) {
  unsigned u = __float_as_uint(f);
  u += 0x7fffu + ((u >> 16) & 1u);   // RTNE
  return (ushort)(u >> 16);
}

// ------- Kernel 1: normalize + cast bf16 + build ids + zero accumulators -------
__global__ __launch_bounds__(256) void k_normalize(
    const float* __restrict__ motion, const float* __restrict__ text,
    const float* __restrict__ shuf, const int* __restrict__ mids,
    ushort* __restrict__ emb, int* __restrict__ ids, float* __restrict__ accs) {
  // fused zeroing of denom/possum/margsum: 3*7168 floats = 5376 float4 = 21 blocks x 256
  if (blockIdx.x < 21) {
    float4 z = {0.f, 0.f, 0.f, 0.f};
    ((float4*)accs)[blockIdx.x * 256 + threadIdx.x] = z;
  }
  int wave = threadIdx.x >> 6;
  int lane = threadIdx.x & 63;
  int row = blockIdx.x * 4 + wave;
  if (row >= N_TOT) return;
  const float* src;
  int id;
  if (row < TEXT_OFF) { src = motion + (size_t)row * DIM; id = mids[row]; }
  else if (row < SHUF_OFF) { int r = row - TEXT_OFF; src = text + (size_t)r * DIM; id = mids[r / 3]; }
  else { int r = row - SHUF_OFF; src = shuf + (size_t)r * DIM; id = mids[r / 3] + 100000; }

  float4 a = ((const float4*)src)[lane * 2];
  float4 b = ((const float4*)src)[lane * 2 + 1];
  float v0 = a.x + 1e-8f, v1 = a.y + 1e-8f, v2 = a.z + 1e-8f, v3 = a.w + 1e-8f;
  float v4 = b.x + 1e-8f, v5 = b.y + 1e-8f, v6 = b.z + 1e-8f, v7 = b.w + 1e-8f;
  float ss = v0*v0 + v1*v1 + v2*v2 + v3*v3 + v4*v4 + v5*v5 + v6*v6 + v7*v7;
  #pragma unroll
  for (int m = 1; m < 64; m <<= 1) ss += __shfl_xor(ss, m);
  float inv = 1.0f / fmaxf(sqrtf(ss), 1e-12f);

  uint w0 = (uint)f2bf(v0 * inv) | ((uint)f2bf(v1 * inv) << 16);
  uint w1 = (uint)f2bf(v2 * inv) | ((uint)f2bf(v3 * inv) << 16);
  uint w2 = (uint)f2bf(v4 * inv) | ((uint)f2bf(v5 * inv) << 16);
  uint w3 = (uint)f2bf(v6 * inv) | ((uint)f2bf(v7 * inv) << 16);
  uint4 pk; pk.x = w0; pk.y = w1; pk.z = w2; pk.w = w3;
  *((uint4*)(emb + (size_t)row * DIM + lane * 8)) = pk;
  if (lane == 0) ids[row] = id;
}

// -------- Kernel 2: symmetric fused A*A^T, 256^2 tiles, 8 waves --------
// m230 minimum-2-phase schedule: STAGE(t+1) || COMPUTE(t), one barrier/step.
// LDS XOR-swizzle with pre-swizzled global source (linear gload_lds dest).
__global__ __launch_bounds__(512, 2) void k_gemm_loss(
    const ushort* __restrict__ emb, const int* __restrict__ ids,
    float* __restrict__ denom, float* __restrict__ possum, float* __restrict__ margsum) {
  __shared__ ushort Asm[2][8192];   // [buf][256 rows x 32 bf16] = 16 KB per buf
  __shared__ ushort Bsm[2][8192];   // total static LDS = 64 KB exactly

  // bijective XCD-chunked swizzle: nwg=406, q=50, r=6
  int orig = blockIdx.x;
  int xcd = orig & 7;
  int idx = orig >> 3;
  int bid = (xcd < 6 ? xcd * 51 : 306 + (xcd - 6) * 50) + idx;

  // triangular tile decode: bid -> (x, y), x <= y
  int x = 0;
  while (bid >= TILES2 - x) { bid -= TILES2 - x; x++; }
  int y = x + bid;
  bool diag = (x == y);
  int brow = x * 256, bcol = y * 256;

  int t = threadIdx.x;
  int l = t & 63;
  int w = t >> 6;
  int wr = w >> 2;           // wave row 0..1  -> 128 output rows
  int wc = w & 3;            // wave col 0..3  -> 64 output cols
  int fr = l & 15;
  int fg = l >> 4;           // 0..3

  // ---- staging constants (per thread) ----
  // chunk c (c=0,1) covers rows [c*128, c*128+128); wave w stages 16 rows/chunk.
  // LDS phys[row][colb] holds logical (row, colb ^ ((row&3)<<4));
  // gload_lds dest is linear, so source col is pre-swizzled:
  int srow = w * 16 + (l >> 2);                       // row within chunk
  int scol = (((l & 3) ^ ((l >> 2) & 3))) * 16;       // swizzled source byte col
  const char* gA = (const char*)emb + (size_t)(brow + srow) * NB + scol;
  const char* gB = (const char*)emb + (size_t)(bcol + srow) * NB + scol;
  int ldso = w * 512;   // ushort offset of this wave's 1 KB chunk slice (lane x16B implicit)

  f32x4 acc[8][4];
  #pragma unroll
  for (int m = 0; m < 8; m++)
    #pragma unroll
    for (int n = 0; n < 4; n++)
      acc[m][n] = (f32x4){0.f, 0.f, 0.f, 0.f};

  // swizzled ds_read column offset (ushorts): logical fg*8 ^ ((fr&3)<<3)
  int swz = (fg * 8) ^ ((fr & 3) << 3);

#define STAGE(T) do { \
    const int _b = (T) & 1; const int _kb = (T) * 64; \
    gload16(gA + _kb,          &Asm[_b][ldso]); \
    gload16(gA + 131072 + _kb, &Asm[_b][4096 + ldso]); \
    gload16(gB + _kb,          &Bsm[_b][ldso]); \
    gload16(gB + 131072 + _kb, &Bsm[_b][4096 + ldso]); \
  } while (0)

#define COMPUTE(T) do { \
    const int _b = (T) & 1; \
    const ushort* Ab = &Asm[_b][(wr * 128 + fr) * 32 + swz]; \
    const ushort* Bb = &Bsm[_b][(wc * 64 + fr) * 32 + swz]; \
    bf16x8 aF[8], bF[4]; \
    _Pragma("unroll") \
    for (int m = 0; m < 8; m++) aF[m] = *(const bf16x8*)(Ab + m * 512); \
    _Pragma("unroll") \
    for (int n = 0; n < 4; n++) bF[n] = *(const bf16x8*)(Bb + n * 512); \
    _Pragma("unroll") \
    for (int m = 0; m < 8; m++) \
      _Pragma("unroll") \
      for (int n = 0; n < 4; n++) \
        acc[m][n] = __builtin_amdgcn_mfma_f32_16x16x32_bf16(aF[m], bF[n], acc[m][n], 0, 0, 0); \
  } while (0)

  STAGE(0);
  __syncthreads();
  #pragma unroll
  for (int tt = 0; tt < 16; tt++) {
    if (tt < 15) STAGE(tt + 1);
    COMPUTE(tt);
    if (tt < 15) __syncthreads();
  }
#undef STAGE
#undef COMPUTE

  // ---- reuse A-buffer LDS for the id arrays ----
  __syncthreads();
  int* ridL = (int*)&Asm[0][0];
  int* cidL = ridL + 256;
  if (t < 256) ridL[t] = ids[brow + t];
  else cidL[t - 256] = ids[bcol + (t - 256)];
  __syncthreads();

  // ---- epilogue: per-element masks + row partials (i) and col partials (j) ----
  int cl = fr;
  int cgrp = fg;
  int cidv[4];
  #pragma unroll
  for (int n = 0; n < 4; n++) cidv[n] = cidL[wc * 64 + n * 16 + cl];
  float cd[4], cp[4], cm[4];
  #pragma unroll
  for (int n = 0; n < 4; n++) { cd[n] = 0.f; cp[n] = 0.f; cm[n] = 0.f; }

  #pragma unroll
  for (int m = 0; m < 8; m++) {
    #pragma unroll
    for (int r = 0; r < 4; r++) {
      int row_l = wr * 128 + m * 16 + cgrp * 4 + r;
      int i = brow + row_l;
      int idi = ridL[row_l];
      float dsum = 0.f, psum = 0.f, msum = 0.f;
      #pragma unroll
      for (int n = 0; n < 4; n++) {
        int col_l = wc * 64 + n * 16 + cl;
        int j = bcol + col_l;
        float sim = acc[m][n][r] * INV_T;
        bool live = (!diag) || (i != j);
        if (live) {
          float e = __expf(sim);
          float hinge = fmaxf(sim + MARGIN_V, 0.f);
          bool same = (idi == cidv[n]);
          float ps = same ? sim : 0.f;
          float ms = same ? 0.f : hinge;
          dsum += e; psum += ps; msum += ms;
          if (!diag) { cd[n] += e; cp[n] += ps; cm[n] += ms; }
        }
      }
      #pragma unroll
      for (int s = 1; s < 16; s <<= 1) {
        dsum += __shfl_xor(dsum, s);
        psum += __shfl_xor(psum, s);
        msum += __shfl_xor(msum, s);
      }
      if (cl == 0) {
        atomicAdd(&denom[i], dsum);
        atomicAdd(&possum[i], psum);
        atomicAdd(&margsum[i], msum);
      }
    }
  }

  if (!diag) {
    #pragma unroll
    for (int n = 0; n < 4; n++) {
      float d = cd[n], p = cp[n], mm = cm[n];
      d += __shfl_xor(d, 16); d += __shfl_xor(d, 32);
      p += __shfl_xor(p, 16); p += __shfl_xor(p, 32);
      mm += __shfl_xor(mm, 16); mm += __shfl_xor(mm, 32);
      if (l < 16) {
        int j = bcol + wc * 64 + n * 16 + cl;
        atomicAdd(&denom[j], d);
        atomicAdd(&possum[j], p);
        atomicAdd(&margsum[j], mm);
      }
    }
  }
}

// ---------------- Kernel 3: finalize ----------------
__global__ __launch_bounds__(256) void k_finalize(
    const int* __restrict__ mids, const float* __restrict__ denom,
    const float* __restrict__ possum, const float* __restrict__ margsum,
    float* __restrict__ out) {
  __shared__ int hist[256];
  __shared__ double red[256];
  __shared__ int redc[256];
  int t = threadIdx.x;
  hist[t] = 0;
  __syncthreads();
  for (int i = t; i < M_ROWS; i += 256) atomicAdd(&hist[mids[i]], 1);
  __syncthreads();

  double tot = 0.0;
  int cnt = 0;
  for (int i = t; i < N_TOT; i += 256) {
    int v; bool shuf = false;
    if (i < TEXT_OFF) v = mids[i];
    else if (i < SHUF_OFF) v = mids[(i - TEXT_OFF) / 3];
    else { v = mids[(i - SHUF_OFF) / 3]; shuf = true; }
    int c = hist[v];
    int npos = shuf ? (3 * c - 1) : (4 * c - 1);
    int nneg = N_TOT - 1 - npos;
    if (npos > 0 && nneg > 0) {
      float infonce = logf(denom[i]) - possum[i] / (float)(npos > 1 ? npos : 1);
      float marg = margsum[i] / (float)(nneg > 1 ? nneg : 1);
      tot += (double)(infonce + marg);
      cnt++;
    }
  }
  red[t] = tot; redc[t] = cnt;
  __syncthreads();
  for (int s = 128; s > 0; s >>= 1) {
    if (t < s) { red[t] += red[t + s]; redc[t] += redc[t + s]; }
    __syncthreads();
  }
  if (t == 0) {
    out[0] = (redc[0] > 0) ? (float)(red[0] / (double)redc[0]) : 0.f;
  }
}

// ---------------- Launch ----------------
extern "C" void kernel_launch(void* const* d_in, const int* in_sizes, int n_in,
                              void* d_out, int out_size, void* d_ws, size_t ws_size,
                              hipStream_t stream) {
  const float* motion = (const float*)d_in[0];
  const float* text   = (const float*)d_in[1];
  const float* shuf   = (const float*)d_in[2];
  const int*   mids   = (const int*)d_in[3];

  char* ws = (char*)d_ws;
  ushort* emb = (ushort*)ws;                                  // N*D bf16 = 7,340,032 B
  int* ids    = (int*)(ws + (size_t)N_TOT * DIM * 2);         // N*4
  float* denom = (float*)(ws + (size_t)N_TOT * DIM * 2 + (size_t)N_TOT * 4);
  float* possum  = denom + N_TOT;
  float* margsum = denom + 2 * N_TOT;

  k_normalize<<<N_TOT / 4, 256, 0, stream>>>(motion, text, shuf, mids, emb, ids, denom);
  k_gemm_loss<<<NBLK2, 512, 0, stream>>>(emb, ids, denom, possum, margsum);
  k_finalize<<<1, 256, 0, stream>>>(mids, denom, possum, margsum, (float*)d_out);
}

// Round 6
// 98.830 us; speedup vs baseline: 1.2122x; 1.1711x over previous
//
#include <hip/hip_runtime.h>

#define M_ROWS 1024
#define DIM 512
#define NB 1024              // row bytes = DIM*2
#define N_TOT 7168           // M + 2*M*C
#define TEXT_OFF 1024
#define SHUF_OFF 4096
#define INV_T (1.0f/0.07f)
#define MARGIN_V 0.2f
#define TILES2 28            // N_TOT / 256
#define NBLK2 406            // 28*29/2 upper-triangular 256^2 tiles
#define SLOT 1536            // floats per partial slot: [2 sides][3 vals][256 rows]

typedef __attribute__((ext_vector_type(8))) short bf16x8;
typedef __attribute__((ext_vector_type(4))) float f32x4;

typedef const __attribute__((address_space(1))) unsigned int gas_uint;
typedef __attribute__((address_space(3))) unsigned int las_uint;

__device__ __forceinline__ void gload16(const void* g, void* l) {
  __builtin_amdgcn_global_load_lds((gas_uint*)g, (las_uint*)l, 16, 0, 0);
}

__device__ __forceinline__ ushort f2bf(float f) {
  unsigned u = __float_as_uint(f);
  u += 0x7fffu + ((u >> 16) & 1u);   // RTNE
  return (ushort)(u >> 16);
}

// ------- Kernel 1: normalize + cast bf16 + build ids -------
__global__ __launch_bounds__(256) void k_normalize(
    const float* __restrict__ motion, const float* __restrict__ text,
    const float* __restrict__ shuf, const int* __restrict__ mids,
    ushort* __restrict__ emb, int* __restrict__ ids) {
  int wave = threadIdx.x >> 6;
  int lane = threadIdx.x & 63;
  int row = blockIdx.x * 4 + wave;
  if (row >= N_TOT) return;
  const float* src;
  int id;
  if (row < TEXT_OFF) { src = motion + (size_t)row * DIM; id = mids[row]; }
  else if (row < SHUF_OFF) { int r = row - TEXT_OFF; src = text + (size_t)r * DIM; id = mids[r / 3]; }
  else { int r = row - SHUF_OFF; src = shuf + (size_t)r * DIM; id = mids[r / 3] + 100000; }

  float4 a = ((const float4*)src)[lane * 2];
  float4 b = ((const float4*)src)[lane * 2 + 1];
  float v0 = a.x + 1e-8f, v1 = a.y + 1e-8f, v2 = a.z + 1e-8f, v3 = a.w + 1e-8f;
  float v4 = b.x + 1e-8f, v5 = b.y + 1e-8f, v6 = b.z + 1e-8f, v7 = b.w + 1e-8f;
  float ss = v0*v0 + v1*v1 + v2*v2 + v3*v3 + v4*v4 + v5*v5 + v6*v6 + v7*v7;
  #pragma unroll
  for (int m = 1; m < 64; m <<= 1) ss += __shfl_xor(ss, m);
  float inv = 1.0f / fmaxf(sqrtf(ss), 1e-12f);

  uint w0 = (uint)f2bf(v0 * inv) | ((uint)f2bf(v1 * inv) << 16);
  uint w1 = (uint)f2bf(v2 * inv) | ((uint)f2bf(v3 * inv) << 16);
  uint w2 = (uint)f2bf(v4 * inv) | ((uint)f2bf(v5 * inv) << 16);
  uint w3 = (uint)f2bf(v6 * inv) | ((uint)f2bf(v7 * inv) << 16);
  uint4 pk; pk.x = w0; pk.y = w1; pk.z = w2; pk.w = w3;
  *((uint4*)(emb + (size_t)row * DIM + lane * 8)) = pk;
  if (lane == 0) ids[row] = id;
}

// -------- Kernel 2: symmetric fused A*A^T, 256^2 tiles, 8 waves --------
// 2-phase schedule; LDS 2-way swizzle (pre-swizzled global source, linear
// gload_lds dest, matching XOR on ds_read). No global atomics: row-side
// partials are combined across the 4 column-waves through LDS, then stored
// contention-free to this block's slot; k_reduce sums slots per row.
__global__ __launch_bounds__(512, 2) void k_gemm_loss(
    const ushort* __restrict__ emb, const int* __restrict__ ids,
    float* __restrict__ part) {
  __shared__ ushort Asm[2][8192];   // [buf][256 rows x 32 bf16] = 16 KB per buf
  __shared__ ushort Bsm[2][8192];   // total static LDS = 64 KB

  // bijective XCD-chunked swizzle: nwg=406, q=50, r=6
  int orig = blockIdx.x;
  int xcd = orig & 7;
  int idx = orig >> 3;
  int bid = (xcd < 6 ? xcd * 51 : 306 + (xcd - 6) * 50) + idx;

  // triangular tile decode: bid -> (x, y), x <= y
  int x = 0;
  while (bid >= TILES2 - x) { bid -= TILES2 - x; x++; }
  int y = x + bid;
  bool diag = (x == y);
  int brow = x * 256, bcol = y * 256;
  int tbid = x * TILES2 - x * (x - 1) / 2 + (y - x);   // linear triangular id

  int t = threadIdx.x;
  int l = t & 63;
  int w = t >> 6;
  int wr = w >> 2;           // wave row 0..1  -> 128 output rows
  int wc = w & 3;            // wave col 0..3  -> 64 output cols
  int fr = l & 15;
  int fg = l >> 4;           // 0..3

  // staging: lane l stages row (w*16 + l>>2) of each 128-row chunk,
  // source col pre-swizzled so linear LDS dest holds the swizzled layout
  int srow = w * 16 + (l >> 2);
  int scol = ((l & 3) ^ ((l >> 3) & 3)) * 16;          // swizzled source byte col
  const char* gA = (const char*)emb + (size_t)(brow + srow) * NB + scol;
  const char* gB = (const char*)emb + (size_t)(bcol + srow) * NB + scol;
  int ldso = w * 512;

  f32x4 acc[8][4];
  #pragma unroll
  for (int m = 0; m < 8; m++)
    #pragma unroll
    for (int n = 0; n < 4; n++)
      acc[m][n] = (f32x4){0.f, 0.f, 0.f, 0.f};

  // swizzled ds_read column offset (ushorts): phys colgroup = fg ^ ((row>>1)&3)
  int swz = (fg ^ ((fr >> 1) & 3)) * 8;

#define STAGE(T) do { \
    const int _b = (T) & 1; const int _kb = (T) * 64; \
    gload16(gA + _kb,          &Asm[_b][ldso]); \
    gload16(gA + 131072 + _kb, &Asm[_b][4096 + ldso]); \
    gload16(gB + _kb,          &Bsm[_b][ldso]); \
    gload16(gB + 131072 + _kb, &Bsm[_b][4096 + ldso]); \
  } while (0)

#define COMPUTE(T) do { \
    const int _b = (T) & 1; \
    const ushort* Ab = &Asm[_b][(wr * 128 + fr) * 32 + swz]; \
    const ushort* Bb = &Bsm[_b][(wc * 64 + fr) * 32 + swz]; \
    bf16x8 aF[8], bF[4]; \
    _Pragma("unroll") \
    for (int m = 0; m < 8; m++) aF[m] = *(const bf16x8*)(Ab + m * 512); \
    _Pragma("unroll") \
    for (int n = 0; n < 4; n++) bF[n] = *(const bf16x8*)(Bb + n * 512); \
    _Pragma("unroll") \
    for (int m = 0; m < 8; m++) \
      _Pragma("unroll") \
      for (int n = 0; n < 4; n++) \
        acc[m][n] = __builtin_amdgcn_mfma_f32_16x16x32_bf16(aF[m], bF[n], acc[m][n], 0, 0, 0); \
  } while (0)

  STAGE(0);
  __syncthreads();
  #pragma unroll
  for (int tt = 0; tt < 16; tt++) {
    if (tt < 15) STAGE(tt + 1);
    COMPUTE(tt);
    if (tt < 15) __syncthreads();
  }
#undef STAGE
#undef COMPUTE

  // ---- reuse LDS after K-loop ----
  // Asm: row-partial exchange rps[8 waves][128 rows] x 3 vals (12 KB)
  // Bsm[0]: col-partial exchange (6 KB); Bsm[1]: rid/cid (2 KB)
  __syncthreads();
  float* rpd = (float*)&Asm[0][0];
  float* rpp = rpd + 1024;
  float* rpm = rpp + 1024;
  float* cps = (float*)&Bsm[0][0];
  int* ridL = (int*)&Bsm[1][0];
  int* cidL = ridL + 256;
  if (t < 256) ridL[t] = ids[brow + t];
  else cidL[t - 256] = ids[bcol + (t - 256)];
  __syncthreads();

  float* ps = part + (size_t)tbid * SLOT;   // [side][3 vals][256]

  // ---- epilogue: per-element masks; per-wave row partials into LDS ----
  int cl = fr;
  int cgrp = fg;
  int cidv[4];
  #pragma unroll
  for (int n = 0; n < 4; n++) cidv[n] = cidL[wc * 64 + n * 16 + cl];
  float cd[4], cp[4], cm[4];
  #pragma unroll
  for (int n = 0; n < 4; n++) { cd[n] = 0.f; cp[n] = 0.f; cm[n] = 0.f; }

  #pragma unroll
  for (int m = 0; m < 8; m++) {
    #pragma unroll
    for (int r = 0; r < 4; r++) {
      int row_l = wr * 128 + m * 16 + cgrp * 4 + r;
      int i = brow + row_l;
      int idi = ridL[row_l];
      float dsum = 0.f, psum = 0.f, msum = 0.f;
      #pragma unroll
      for (int n = 0; n < 4; n++) {
        int col_l = wc * 64 + n * 16 + cl;
        int j = bcol + col_l;
        float sim = acc[m][n][r] * INV_T;
        bool live = (!diag) || (i != j);
        if (live) {
          float e = __expf(sim);
          float hinge = fmaxf(sim + MARGIN_V, 0.f);
          bool same = (idi == cidv[n]);
          float psv = same ? sim : 0.f;
          float msv = same ? 0.f : hinge;
          dsum += e; psum += psv; msum += msv;
          if (!diag) { cd[n] += e; cp[n] += psv; cm[n] += msv; }
        }
      }
      #pragma unroll
      for (int s = 1; s < 16; s <<= 1) {
        dsum += __shfl_xor(dsum, s);
        psum += __shfl_xor(psum, s);
        msum += __shfl_xor(msum, s);
      }
      if (cl == 0) {            // per-wave slice: rps[w][row within 128]
        int o = w * 128 + (row_l & 127);
        rpd[o] = dsum; rpp[o] = psum; rpm[o] = msum;
      }
    }
  }

  if (!diag) {
    // col partials: shfl-combine the 4 row-groups within the wave, park in LDS
    #pragma unroll
    for (int n = 0; n < 4; n++) {
      float d = cd[n], p = cp[n], mm = cm[n];
      d += __shfl_xor(d, 16); d += __shfl_xor(d, 32);
      p += __shfl_xor(p, 16); p += __shfl_xor(p, 32);
      mm += __shfl_xor(mm, 16); mm += __shfl_xor(mm, 32);
      if (l < 16) {
        int o = ((w * 4 + n) * 16 + cl) * 3;
        cps[o] = d; cps[o + 1] = p; cps[o + 2] = mm;
      }
    }
  }
  __syncthreads();

  // row side: sum the 4 wc-wave slices, coalesced store
  if (t < 256) {
    int b0 = (t >> 7) * 512 + (t & 127);   // wr block base in rps
    float d = rpd[b0] + rpd[b0 + 128] + rpd[b0 + 256] + rpd[b0 + 384];
    float p = rpp[b0] + rpp[b0 + 128] + rpp[b0 + 256] + rpp[b0 + 384];
    float mm = rpm[b0] + rpm[b0 + 128] + rpm[b0 + 256] + rpm[b0 + 384];
    ps[t] = d; ps[256 + t] = p; ps[512 + t] = mm;
  }
  // col side: combine wr=0/wr=1 wave pairs, store (non-diag only; k_reduce
  // never reads the diag col side)
  if (!diag && wr == 0 && l < 16) {
    #pragma unroll
    for (int n = 0; n < 4; n++) {
      int o0 = ((w * 4 + n) * 16 + cl) * 3;
      int o1 = (((w + 4) * 4 + n) * 16 + cl) * 3;
      int col_l = wc * 64 + n * 16 + cl;
      ps[768 + col_l] = cps[o0] + cps[o1];
      ps[768 + 256 + col_l] = cps[o0 + 1] + cps[o1 + 1];
      ps[768 + 512 + col_l] = cps[o0 + 2] + cps[o1 + 2];
    }
  }
}

// ---------------- Kernel 3: reduce partials into per-row sums ----------------
__global__ __launch_bounds__(256) void k_reduce(
    const float* __restrict__ part, float* __restrict__ denom,
    float* __restrict__ possum, float* __restrict__ margsum) {
  int i = blockIdx.x * 256 + threadIdx.x;   // row 0..7167
  int p = i >> 8;                           // panel 0..27 (block-uniform)
  int v = i & 255;
  float d = 0.f, pp = 0.f, mm = 0.f;
  int base = p * TILES2 - p * (p - 1) / 2;  // tbid(p, p)
  for (int yy = p; yy < TILES2; yy++) {     // row-side from tiles (p, yy)
    const float* s = part + (size_t)(base + yy - p) * SLOT;
    d += s[v]; pp += s[256 + v]; mm += s[512 + v];
  }
  for (int xx = 0; xx < p; xx++) {          // col-side from tiles (xx, p)
    int b = xx * TILES2 - xx * (xx - 1) / 2 + (p - xx);
    const float* s = part + (size_t)b * SLOT + 768;
    d += s[v]; pp += s[256 + v]; mm += s[512 + v];
  }
  denom[i] = d; possum[i] = pp; margsum[i] = mm;
}

// ---------------- Kernel 4: finalize ----------------
__global__ __launch_bounds__(256) void k_finalize(
    const int* __restrict__ mids, const float* __restrict__ denom,
    const float* __restrict__ possum, const float* __restrict__ margsum,
    float* __restrict__ out) {
  __shared__ int hist[256];
  __shared__ double red[256];
  __shared__ int redc[256];
  int t = threadIdx.x;
  hist[t] = 0;
  __syncthreads();
  for (int i = t; i < M_ROWS; i += 256) atomicAdd(&hist[mids[i]], 1);
  __syncthreads();

  double tot = 0.0;
  int cnt = 0;
  for (int i = t; i < N_TOT; i += 256) {
    int v; bool shuf = false;
    if (i < TEXT_OFF) v = mids[i];
    else if (i < SHUF_OFF) v = mids[(i - TEXT_OFF) / 3];
    else { v = mids[(i - SHUF_OFF) / 3]; shuf = true; }
    int c = hist[v];
    int npos = shuf ? (3 * c - 1) : (4 * c - 1);
    int nneg = N_TOT - 1 - npos;
    if (npos > 0 && nneg > 0) {
      float infonce = logf(denom[i]) - possum[i] / (float)(npos > 1 ? npos : 1);
      float marg = margsum[i] / (float)(nneg > 1 ? nneg : 1);
      tot += (double)(infonce + marg);
      cnt++;
    }
  }
  red[t] = tot; redc[t] = cnt;
  __syncthreads();
  for (int s = 128; s > 0; s >>= 1) {
    if (t < s) { red[t] += red[t + s]; redc[t] += redc[t + s]; }
    __syncthreads();
  }
  if (t == 0) {
    out[0] = (redc[0] > 0) ? (float)(red[0] / (double)redc[0]) : 0.f;
  }
}

// ---------------- Launch ----------------
extern "C" void kernel_launch(void* const* d_in, const int* in_sizes, int n_in,
                              void* d_out, int out_size, void* d_ws, size_t ws_size,
                              hipStream_t stream) {
  const float* motion = (const float*)d_in[0];
  const float* text   = (const float*)d_in[1];
  const float* shuf   = (const float*)d_in[2];
  const int*   mids   = (const int*)d_in[3];

  char* ws = (char*)d_ws;
  ushort* emb = (ushort*)ws;                                  // 7,340,032 B
  int* ids    = (int*)(ws + (size_t)N_TOT * DIM * 2);         // 28,672 B
  float* denom = (float*)(ws + 7368704);                      // 3*7168*4 = 86,016 B
  float* possum  = denom + N_TOT;
  float* margsum = denom + 2 * N_TOT;
  float* part = (float*)(ws + 7454720);                       // 406*1536*4 = 2,494,464 B

  k_normalize<<<N_TOT / 4, 256, 0, stream>>>(motion, text, shuf, mids, emb, ids);
  k_gemm_loss<<<NBLK2, 512, 0, stream>>>(emb, ids, part);
  k_reduce<<<TILES2, 256, 0, stream>>>(part, denom, possum, margsum);
  k_finalize<<<1, 256, 0, stream>>>(mids, denom, possum, margsum, (float*)d_out);
}

// Round 7
// 97.563 us; speedup vs baseline: 1.2279x; 1.0130x over previous
//
#include <hip/hip_runtime.h>

#define M_ROWS 1024
#define DIM 512
#define NB 1024              // row bytes = DIM*2
#define N_TOT 7168           // M + 2*M*C
#define TEXT_OFF 1024
#define SHUF_OFF 4096
#define INV_T (1.0f/0.07f)
#define MARGIN_V 0.2f
#define TILES2 28            // N_TOT / 256
#define NBLK2 406            // 28*29/2 upper-triangular 256^2 tiles
#define SLOT 1536            // floats per partial slot: [2 sides][3 vals][256 rows]

typedef __attribute__((ext_vector_type(8))) short bf16x8;
typedef __attribute__((ext_vector_type(4))) float f32x4;

typedef const __attribute__((address_space(1))) unsigned int gas_uint;
typedef __attribute__((address_space(3))) unsigned int las_uint;

__device__ __forceinline__ void gload16(const void* g, void* l) {
  __builtin_amdgcn_global_load_lds((gas_uint*)g, (las_uint*)l, 16, 0, 0);
}

__device__ __forceinline__ ushort f2bf(float f) {
  unsigned u = __float_as_uint(f);
  u += 0x7fffu + ((u >> 16) & 1u);   // RTNE
  return (ushort)(u >> 16);
}

// ------- Kernel 1: normalize + cast bf16 + build ids -------
__global__ __launch_bounds__(256) void k_normalize(
    const float* __restrict__ motion, const float* __restrict__ text,
    const float* __restrict__ shuf, const int* __restrict__ mids,
    ushort* __restrict__ emb, int* __restrict__ ids) {
  int wave = threadIdx.x >> 6;
  int lane = threadIdx.x & 63;
  int row = blockIdx.x * 4 + wave;
  if (row >= N_TOT) return;
  const float* src;
  int id;
  if (row < TEXT_OFF) { src = motion + (size_t)row * DIM; id = mids[row]; }
  else if (row < SHUF_OFF) { int r = row - TEXT_OFF; src = text + (size_t)r * DIM; id = mids[r / 3]; }
  else { int r = row - SHUF_OFF; src = shuf + (size_t)r * DIM; id = mids[r / 3] + 100000; }

  float4 a = ((const float4*)src)[lane * 2];
  float4 b = ((const float4*)src)[lane * 2 + 1];
  float v0 = a.x + 1e-8f, v1 = a.y + 1e-8f, v2 = a.z + 1e-8f, v3 = a.w + 1e-8f;
  float v4 = b.x + 1e-8f, v5 = b.y + 1e-8f, v6 = b.z + 1e-8f, v7 = b.w + 1e-8f;
  float ss = v0*v0 + v1*v1 + v2*v2 + v3*v3 + v4*v4 + v5*v5 + v6*v6 + v7*v7;
  #pragma unroll
  for (int m = 1; m < 64; m <<= 1) ss += __shfl_xor(ss, m);
  float inv = 1.0f / fmaxf(sqrtf(ss), 1e-12f);

  uint w0 = (uint)f2bf(v0 * inv) | ((uint)f2bf(v1 * inv) << 16);
  uint w1 = (uint)f2bf(v2 * inv) | ((uint)f2bf(v3 * inv) << 16);
  uint w2 = (uint)f2bf(v4 * inv) | ((uint)f2bf(v5 * inv) << 16);
  uint w3 = (uint)f2bf(v6 * inv) | ((uint)f2bf(v7 * inv) << 16);
  uint4 pk; pk.x = w0; pk.y = w1; pk.z = w2; pk.w = w3;
  *((uint4*)(emb + (size_t)row * DIM + lane * 8)) = pk;
  if (lane == 0) ids[row] = id;
}

// -------- Kernel 2: symmetric fused A*A^T, 256^2 tiles, 8 waves --------
// Counted-vmcnt pipeline (T3/T4): stage tile t+2 into the buffer freed by
// tile t's reads; raw s_barrier (no vmcnt(0) drain); vmcnt(4) retires only
// the next tile's loads. LDS 2-way swizzle (pre-swizzled source / XOR read).
// No global atomics: partials to private slots, k_reduce sums them.
__global__ __launch_bounds__(512, 2) void k_gemm_loss(
    const ushort* __restrict__ emb, const int* __restrict__ ids,
    float* __restrict__ part) {
  __shared__ ushort Asm[2][8192];   // [buf][256 rows x 32 bf16] = 16 KB per buf
  __shared__ ushort Bsm[2][8192];   // total static LDS = 64 KB

  // bijective XCD-chunked swizzle: nwg=406, q=50, r=6
  int orig = blockIdx.x;
  int xcd = orig & 7;
  int idx = orig >> 3;
  int bid = (xcd < 6 ? xcd * 51 : 306 + (xcd - 6) * 50) + idx;

  // triangular tile decode: bid -> (x, y), x <= y
  int x = 0;
  while (bid >= TILES2 - x) { bid -= TILES2 - x; x++; }
  int y = x + bid;
  bool diag = (x == y);
  int brow = x * 256, bcol = y * 256;
  int tbid = x * TILES2 - x * (x - 1) / 2 + (y - x);   // linear triangular id

  int t = threadIdx.x;
  int l = t & 63;
  int w = t >> 6;
  int wr = w >> 2;           // wave row 0..1  -> 128 output rows
  int wc = w & 3;            // wave col 0..3  -> 64 output cols
  int fr = l & 15;
  int fg = l >> 4;           // 0..3

  // staging: lane l stages row (w*16 + l>>2) of each 128-row chunk,
  // source col pre-swizzled so linear LDS dest holds the swizzled layout
  int srow = w * 16 + (l >> 2);
  int scol = ((l & 3) ^ ((l >> 3) & 3)) * 16;          // swizzled source byte col
  const char* gA = (const char*)emb + (size_t)(brow + srow) * NB + scol;
  const char* gB = (const char*)emb + (size_t)(bcol + srow) * NB + scol;
  int ldso = w * 512;

  f32x4 acc[8][4];
  #pragma unroll
  for (int m = 0; m < 8; m++)
    #pragma unroll
    for (int n = 0; n < 4; n++)
      acc[m][n] = (f32x4){0.f, 0.f, 0.f, 0.f};

  // swizzled ds_read column offset (ushorts): phys colgroup = fg ^ ((row>>1)&3)
  int swz = (fg ^ ((fr >> 1) & 3)) * 8;

#define STAGE(T) do { \
    const int _b = (T) & 1; const int _kb = (T) * 64; \
    gload16(gA + _kb,          &Asm[_b][ldso]); \
    gload16(gA + 131072 + _kb, &Asm[_b][4096 + ldso]); \
    gload16(gB + _kb,          &Bsm[_b][ldso]); \
    gload16(gB + 131072 + _kb, &Bsm[_b][4096 + ldso]); \
  } while (0)

  // prologue: tiles 0 and 1 in flight; wait tile 0 only
  STAGE(0);
  STAGE(1);
  asm volatile("s_waitcnt vmcnt(4)" ::: "memory");
  __builtin_amdgcn_s_barrier();

  #pragma unroll
  for (int tt = 0; tt < 16; tt++) {
    const int _b = tt & 1;
    const ushort* Ab = &Asm[_b][(wr * 128 + fr) * 32 + swz];
    const ushort* Bb = &Bsm[_b][(wc * 64 + fr) * 32 + swz];
    bf16x8 aF[8], bF[4];
    #pragma unroll
    for (int m = 0; m < 8; m++) aF[m] = *(const bf16x8*)(Ab + m * 512);
    #pragma unroll
    for (int n = 0; n < 4; n++) bF[n] = *(const bf16x8*)(Bb + n * 512);
    // all of this wave's reads from buf[_b] complete, then rendezvous so
    // no wave overwrites a buffer another wave is still reading
    asm volatile("s_waitcnt lgkmcnt(0)" ::: "memory");
    __builtin_amdgcn_s_barrier();
    if (tt + 2 < 16) STAGE(tt + 2);   // refill the just-freed buffer
    __builtin_amdgcn_s_setprio(1);
    #pragma unroll
    for (int m = 0; m < 8; m++)
      #pragma unroll
      for (int n = 0; n < 4; n++)
        acc[m][n] = __builtin_amdgcn_mfma_f32_16x16x32_bf16(aF[m], bF[n], acc[m][n], 0, 0, 0);
    __builtin_amdgcn_s_setprio(0);
    if (tt < 14) {
      // outstanding: tile tt+1 (4) + tile tt+2 (4); retire tile tt+1 only
      asm volatile("s_waitcnt vmcnt(4)" ::: "memory");
      __builtin_amdgcn_s_barrier();
    } else if (tt == 14) {
      asm volatile("s_waitcnt vmcnt(0)" ::: "memory");
      __builtin_amdgcn_s_barrier();
    }
  }
#undef STAGE

  // ---- reuse LDS after K-loop ----
  // Asm: row-partial exchange rps[8 waves][128 rows] x 3 vals (12 KB)
  // Bsm[0]: col-partial exchange (6 KB); Bsm[1]: rid/cid (2 KB)
  __syncthreads();
  float* rpd = (float*)&Asm[0][0];
  float* rpp = rpd + 1024;
  float* rpm = rpp + 1024;
  float* cps = (float*)&Bsm[0][0];
  int* ridL = (int*)&Bsm[1][0];
  int* cidL = ridL + 256;
  if (t < 256) ridL[t] = ids[brow + t];
  else cidL[t - 256] = ids[bcol + (t - 256)];
  __syncthreads();

  float* ps = part + (size_t)tbid * SLOT;   // [side][3 vals][256]

  // ---- epilogue: per-element masks; per-wave row partials into LDS ----
  int cl = fr;
  int cgrp = fg;
  int cidv[4];
  #pragma unroll
  for (int n = 0; n < 4; n++) cidv[n] = cidL[wc * 64 + n * 16 + cl];
  float cd[4], cp[4], cm[4];
  #pragma unroll
  for (int n = 0; n < 4; n++) { cd[n] = 0.f; cp[n] = 0.f; cm[n] = 0.f; }

  #pragma unroll
  for (int m = 0; m < 8; m++) {
    #pragma unroll
    for (int r = 0; r < 4; r++) {
      int row_l = wr * 128 + m * 16 + cgrp * 4 + r;
      int i = brow + row_l;
      int idi = ridL[row_l];
      float dsum = 0.f, psum = 0.f, msum = 0.f;
      #pragma unroll
      for (int n = 0; n < 4; n++) {
        int col_l = wc * 64 + n * 16 + cl;
        int j = bcol + col_l;
        float sim = acc[m][n][r] * INV_T;
        bool live = (!diag) || (i != j);
        if (live) {
          float e = __expf(sim);
          float hinge = fmaxf(sim + MARGIN_V, 0.f);
          bool same = (idi == cidv[n]);
          float psv = same ? sim : 0.f;
          float msv = same ? 0.f : hinge;
          dsum += e; psum += psv; msum += msv;
          if (!diag) { cd[n] += e; cp[n] += psv; cm[n] += msv; }
        }
      }
      #pragma unroll
      for (int s = 1; s < 16; s <<= 1) {
        dsum += __shfl_xor(dsum, s);
        psum += __shfl_xor(psum, s);
        msum += __shfl_xor(msum, s);
      }
      if (cl == 0) {            // per-wave slice: rps[w][row within 128]
        int o = w * 128 + (row_l & 127);
        rpd[o] = dsum; rpp[o] = psum; rpm[o] = msum;
      }
    }
  }

  if (!diag) {
    // col partials: shfl-combine the 4 row-groups within the wave, park in LDS
    #pragma unroll
    for (int n = 0; n < 4; n++) {
      float d = cd[n], p = cp[n], mm = cm[n];
      d += __shfl_xor(d, 16); d += __shfl_xor(d, 32);
      p += __shfl_xor(p, 16); p += __shfl_xor(p, 32);
      mm += __shfl_xor(mm, 16); mm += __shfl_xor(mm, 32);
      if (l < 16) {
        int o = ((w * 4 + n) * 16 + cl) * 3;
        cps[o] = d; cps[o + 1] = p; cps[o + 2] = mm;
      }
    }
  }
  __syncthreads();

  // row side: sum the 4 wc-wave slices, coalesced store
  if (t < 256) {
    int b0 = (t >> 7) * 512 + (t & 127);   // wr block base in rps
    float d = rpd[b0] + rpd[b0 + 128] + rpd[b0 + 256] + rpd[b0 + 384];
    float p = rpp[b0] + rpp[b0 + 128] + rpp[b0 + 256] + rpp[b0 + 384];
    float mm = rpm[b0] + rpm[b0 + 128] + rpm[b0 + 256] + rpm[b0 + 384];
    ps[t] = d; ps[256 + t] = p; ps[512 + t] = mm;
  }
  // col side: combine wr=0/wr=1 wave pairs, store (non-diag only; k_reduce
  // never reads the diag col side)
  if (!diag && wr == 0 && l < 16) {
    #pragma unroll
    for (int n = 0; n < 4; n++) {
      int o0 = ((w * 4 + n) * 16 + cl) * 3;
      int o1 = (((w + 4) * 4 + n) * 16 + cl) * 3;
      int col_l = wc * 64 + n * 16 + cl;
      ps[768 + col_l] = cps[o0] + cps[o1];
      ps[768 + 256 + col_l] = cps[o0 + 1] + cps[o1 + 1];
      ps[768 + 512 + col_l] = cps[o0 + 2] + cps[o1 + 2];
    }
  }
}

// ---------------- Kernel 3: reduce partials into per-row sums ----------------
__global__ __launch_bounds__(256) void k_reduce(
    const float* __restrict__ part, float* __restrict__ denom,
    float* __restrict__ possum, float* __restrict__ margsum) {
  int i = blockIdx.x * 256 + threadIdx.x;   // row 0..7167
  int p = i >> 8;                           // panel 0..27 (block-uniform)
  int v = i & 255;
  float d = 0.f, pp = 0.f, mm = 0.f;
  int base = p * TILES2 - p * (p - 1) / 2;  // tbid(p, p)
  for (int yy = p; yy < TILES2; yy++) {     // row-side from tiles (p, yy)
    const float* s = part + (size_t)(base + yy - p) * SLOT;
    d += s[v]; pp += s[256 + v]; mm += s[512 + v];
  }
  for (int xx = 0; xx < p; xx++) {          // col-side from tiles (xx, p)
    int b = xx * TILES2 - xx * (xx - 1) / 2 + (p - xx);
    const float* s = part + (size_t)b * SLOT + 768;
    d += s[v]; pp += s[256 + v]; mm += s[512 + v];
  }
  denom[i] = d; possum[i] = pp; margsum[i] = mm;
}

// ---------------- Kernel 4: finalize ----------------
__global__ __launch_bounds__(256) void k_finalize(
    const int* __restrict__ mids, const float* __restrict__ denom,
    const float* __restrict__ possum, const float* __restrict__ margsum,
    float* __restrict__ out) {
  __shared__ int hist[256];
  __shared__ double red[256];
  __shared__ int redc[256];
  int t = threadIdx.x;
  hist[t] = 0;
  __syncthreads();
  for (int i = t; i < M_ROWS; i += 256) atomicAdd(&hist[mids[i]], 1);
  __syncthreads();

  double tot = 0.0;
  int cnt = 0;
  for (int i = t; i < N_TOT; i += 256) {
    int v; bool shuf = false;
    if (i < TEXT_OFF) v = mids[i];
    else if (i < SHUF_OFF) v = mids[(i - TEXT_OFF) / 3];
    else { v = mids[(i - SHUF_OFF) / 3]; shuf = true; }
    int c = hist[v];
    int npos = shuf ? (3 * c - 1) : (4 * c - 1);
    int nneg = N_TOT - 1 - npos;
    if (npos > 0 && nneg > 0) {
      float infonce = logf(denom[i]) - possum[i] / (float)(npos > 1 ? npos : 1);
      float marg = margsum[i] / (float)(nneg > 1 ? nneg : 1);
      tot += (double)(infonce + marg);
      cnt++;
    }
  }
  red[t] = tot; redc[t] = cnt;
  __syncthreads();
  for (int s = 128; s > 0; s >>= 1) {
    if (t < s) { red[t] += red[t + s]; redc[t] += redc[t + s]; }
    __syncthreads();
  }
  if (t == 0) {
    out[0] = (redc[0] > 0) ? (float)(red[0] / (double)redc[0]) : 0.f;
  }
}

// ---------------- Launch ----------------
extern "C" void kernel_launch(void* const* d_in, const int* in_sizes, int n_in,
                              void* d_out, int out_size, void* d_ws, size_t ws_size,
                              hipStream_t stream) {
  const float* motion = (const float*)d_in[0];
  const float* text   = (const float*)d_in[1];
  const float* shuf   = (const float*)d_in[2];
  const int*   mids   = (const int*)d_in[3];

  char* ws = (char*)d_ws;
  ushort* emb = (ushort*)ws;                                  // 7,340,032 B
  int* ids    = (int*)(ws + (size_t)N_TOT * DIM * 2);         // 28,672 B
  float* denom = (float*)(ws + 7368704);                      // 3*7168*4 = 86,016 B
  float* possum  = denom + N_TOT;
  float* margsum = denom + 2 * N_TOT;
  float* part = (float*)(ws + 7454720);                       // 406*1536*4 = 2,494,464 B

  k_normalize<<<N_TOT / 4, 256, 0, stream>>>(motion, text, shuf, mids, emb, ids);
  k_gemm_loss<<<NBLK2, 512, 0, stream>>>(emb, ids, part);
  k_reduce<<<TILES2, 256, 0, stream>>>(part, denom, possum, margsum);
  k_finalize<<<1, 256, 0, stream>>>(mids, denom, possum, margsum, (float*)d_out);
}

// Round 8
// 81.606 us; speedup vs baseline: 1.4680x; 1.1955x over previous
//
#include <hip/hip_runtime.h>

#define M_ROWS 1024
#define DIM 512
#define NB 1024              // row bytes = DIM*2
#define N_TOT 7168           // M + 2*M*C
#define TEXT_OFF 1024
#define SHUF_OFF 4096
#define INV_T (1.0f/0.07f)
#define MARGIN_V 0.2f
#define TILES2 28            // N_TOT / 256
#define NBLK2 406            // 28*29/2 upper-triangular 256^2 tiles
#define SLOT 1536            // floats per partial slot: [2 sides][3 vals][256 rows]

typedef __attribute__((ext_vector_type(8))) short bf16x8;
typedef __attribute__((ext_vector_type(4))) float f32x4;

typedef const __attribute__((address_space(1))) unsigned int gas_uint;
typedef __attribute__((address_space(3))) unsigned int las_uint;

__device__ __forceinline__ void gload16(const void* g, void* l) {
  __builtin_amdgcn_global_load_lds((gas_uint*)g, (las_uint*)l, 16, 0, 0);
}

__device__ __forceinline__ ushort f2bf(float f) {
  unsigned u = __float_as_uint(f);
  u += 0x7fffu + ((u >> 16) & 1u);   // RTNE
  return (ushort)(u >> 16);
}

// ------- Kernel 1: normalize + cast bf16 + build ids -------
__global__ __launch_bounds__(256) void k_normalize(
    const float* __restrict__ motion, const float* __restrict__ text,
    const float* __restrict__ shuf, const int* __restrict__ mids,
    ushort* __restrict__ emb, int* __restrict__ ids) {
  int wave = threadIdx.x >> 6;
  int lane = threadIdx.x & 63;
  int row = blockIdx.x * 4 + wave;
  if (row >= N_TOT) return;
  const float* src;
  int id;
  if (row < TEXT_OFF) { src = motion + (size_t)row * DIM; id = mids[row]; }
  else if (row < SHUF_OFF) { int r = row - TEXT_OFF; src = text + (size_t)r * DIM; id = mids[r / 3]; }
  else { int r = row - SHUF_OFF; src = shuf + (size_t)r * DIM; id = mids[r / 3] + 100000; }

  float4 a = ((const float4*)src)[lane * 2];
  float4 b = ((const float4*)src)[lane * 2 + 1];
  float v0 = a.x + 1e-8f, v1 = a.y + 1e-8f, v2 = a.z + 1e-8f, v3 = a.w + 1e-8f;
  float v4 = b.x + 1e-8f, v5 = b.y + 1e-8f, v6 = b.z + 1e-8f, v7 = b.w + 1e-8f;
  float ss = v0*v0 + v1*v1 + v2*v2 + v3*v3 + v4*v4 + v5*v5 + v6*v6 + v7*v7;
  #pragma unroll
  for (int m = 1; m < 64; m <<= 1) ss += __shfl_xor(ss, m);
  float inv = 1.0f / fmaxf(sqrtf(ss), 1e-12f);

  uint w0 = (uint)f2bf(v0 * inv) | ((uint)f2bf(v1 * inv) << 16);
  uint w1 = (uint)f2bf(v2 * inv) | ((uint)f2bf(v3 * inv) << 16);
  uint w2 = (uint)f2bf(v4 * inv) | ((uint)f2bf(v5 * inv) << 16);
  uint w3 = (uint)f2bf(v6 * inv) | ((uint)f2bf(v7 * inv) << 16);
  uint4 pk; pk.x = w0; pk.y = w1; pk.z = w2; pk.w = w3;
  *((uint4*)(emb + (size_t)row * DIM + lane * 8)) = pk;
  if (lane == 0) ids[row] = id;
}

// -------- Kernel 2: symmetric fused A*A^T, 256^2 tiles, 8 waves --------
// TRIPLE-buffered LDS (96 KB, 1 block/CU): STAGE(t+2) targets buf[(t+2)%3],
// disjoint from buf[t%3] being read -> no mid-step lgkmcnt(0) rendezvous.
// ds_read and MFMA are compiler-interleaved (fine-grained lgkmcnt); one
// barrier + counted vmcnt(4) per step. LDS 2-way swizzle as before.
__global__ __launch_bounds__(512, 2) void k_gemm_loss(
    const ushort* __restrict__ emb, const int* __restrict__ ids,
    float* __restrict__ part) {
  __shared__ ushort Asm[3][8192];   // [buf][256 rows x 32 bf16] = 16 KB per buf
  __shared__ ushort Bsm[3][8192];   // total static LDS = 96 KB

  // bijective XCD-chunked swizzle: nwg=406, q=50, r=6
  int orig = blockIdx.x;
  int xcd = orig & 7;
  int idx = orig >> 3;
  int bid = (xcd < 6 ? xcd * 51 : 306 + (xcd - 6) * 50) + idx;

  // triangular tile decode: bid -> (x, y), x <= y
  int x = 0;
  while (bid >= TILES2 - x) { bid -= TILES2 - x; x++; }
  int y = x + bid;
  bool diag = (x == y);
  int brow = x * 256, bcol = y * 256;
  int tbid = x * TILES2 - x * (x - 1) / 2 + (y - x);   // linear triangular id

  int t = threadIdx.x;
  int l = t & 63;
  int w = t >> 6;
  int wr = w >> 2;           // wave row 0..1  -> 128 output rows
  int wc = w & 3;            // wave col 0..3  -> 64 output cols
  int fr = l & 15;
  int fg = l >> 4;           // 0..3

  // staging: lane l stages row (w*16 + l>>2) of each 128-row chunk,
  // source col pre-swizzled so linear LDS dest holds the swizzled layout
  int srow = w * 16 + (l >> 2);
  int scol = ((l & 3) ^ ((l >> 3) & 3)) * 16;          // swizzled source byte col
  const char* gA = (const char*)emb + (size_t)(brow + srow) * NB + scol;
  const char* gB = (const char*)emb + (size_t)(bcol + srow) * NB + scol;
  int ldso = w * 512;

  f32x4 acc[8][4];
  #pragma unroll
  for (int m = 0; m < 8; m++)
    #pragma unroll
    for (int n = 0; n < 4; n++)
      acc[m][n] = (f32x4){0.f, 0.f, 0.f, 0.f};

  // swizzled ds_read column offset (ushorts): phys colgroup = fg ^ ((row>>1)&3)
  int swz = (fg ^ ((fr >> 1) & 3)) * 8;

#define STAGE(T) do { \
    const int _b = (T) % 3; const int _kb = (T) * 64; \
    gload16(gA + _kb,          &Asm[_b][ldso]); \
    gload16(gA + 131072 + _kb, &Asm[_b][4096 + ldso]); \
    gload16(gB + _kb,          &Bsm[_b][ldso]); \
    gload16(gB + 131072 + _kb, &Bsm[_b][4096 + ldso]); \
  } while (0)

  // prologue: tiles 0 and 1 in flight; wait tile 0 only
  STAGE(0);
  STAGE(1);
  asm volatile("s_waitcnt vmcnt(4)" ::: "memory");
  __builtin_amdgcn_s_barrier();

  #pragma unroll
  for (int tt = 0; tt < 16; tt++) {
    if (tt + 2 < 16) STAGE(tt + 2);   // disjoint buffer: no read conflict
    const int _b = tt % 3;
    const ushort* Ab = &Asm[_b][(wr * 128 + fr) * 32 + swz];
    const ushort* Bb = &Bsm[_b][(wc * 64 + fr) * 32 + swz];
    bf16x8 aF[8], bF[4];
    #pragma unroll
    for (int m = 0; m < 8; m++) aF[m] = *(const bf16x8*)(Ab + m * 512);
    #pragma unroll
    for (int n = 0; n < 4; n++) bF[n] = *(const bf16x8*)(Bb + n * 512);
    __builtin_amdgcn_s_setprio(1);
    #pragma unroll
    for (int m = 0; m < 8; m++)
      #pragma unroll
      for (int n = 0; n < 4; n++)
        acc[m][n] = __builtin_amdgcn_mfma_f32_16x16x32_bf16(aF[m], bF[n], acc[m][n], 0, 0, 0);
    __builtin_amdgcn_s_setprio(0);
    if (tt < 14) {
      // outstanding: tile tt+1 (4) + tile tt+2 (4); retire tile tt+1 only
      asm volatile("s_waitcnt vmcnt(4)" ::: "memory");
      __builtin_amdgcn_s_barrier();
    } else if (tt == 14) {
      asm volatile("s_waitcnt vmcnt(0)" ::: "memory");
      __builtin_amdgcn_s_barrier();
    }
  }
#undef STAGE

  // ---- reuse LDS after K-loop ----
  // Asm[0..1]: row-partial exchange rps[8 waves][128 rows] x 3 vals (12 KB)
  // Bsm[0]: col-partial exchange (6 KB); Bsm[1]: rid/cid (2 KB)
  __syncthreads();
  float* rpd = (float*)&Asm[0][0];
  float* rpp = rpd + 1024;
  float* rpm = rpp + 1024;
  float* cps = (float*)&Bsm[0][0];
  int* ridL = (int*)&Bsm[1][0];
  int* cidL = ridL + 256;
  if (t < 256) ridL[t] = ids[brow + t];
  else cidL[t - 256] = ids[bcol + (t - 256)];
  __syncthreads();

  float* ps = part + (size_t)tbid * SLOT;   // [side][3 vals][256]

  // ---- epilogue: per-element masks; per-wave row partials into LDS ----
  int cl = fr;
  int cgrp = fg;
  int cidv[4];
  #pragma unroll
  for (int n = 0; n < 4; n++) cidv[n] = cidL[wc * 64 + n * 16 + cl];
  float cd[4], cp[4], cm[4];
  #pragma unroll
  for (int n = 0; n < 4; n++) { cd[n] = 0.f; cp[n] = 0.f; cm[n] = 0.f; }

  #pragma unroll
  for (int m = 0; m < 8; m++) {
    #pragma unroll
    for (int r = 0; r < 4; r++) {
      int row_l = wr * 128 + m * 16 + cgrp * 4 + r;
      int i = brow + row_l;
      int idi = ridL[row_l];
      float dsum = 0.f, psum = 0.f, msum = 0.f;
      #pragma unroll
      for (int n = 0; n < 4; n++) {
        int col_l = wc * 64 + n * 16 + cl;
        int j = bcol + col_l;
        float sim = acc[m][n][r] * INV_T;
        bool live = (!diag) || (i != j);
        if (live) {
          float e = __expf(sim);
          float hinge = fmaxf(sim + MARGIN_V, 0.f);
          bool same = (idi == cidv[n]);
          float psv = same ? sim : 0.f;
          float msv = same ? 0.f : hinge;
          dsum += e; psum += psv; msum += msv;
          if (!diag) { cd[n] += e; cp[n] += psv; cm[n] += msv; }
        }
      }
      #pragma unroll
      for (int s = 1; s < 16; s <<= 1) {
        dsum += __shfl_xor(dsum, s);
        psum += __shfl_xor(psum, s);
        msum += __shfl_xor(msum, s);
      }
      if (cl == 0) {            // per-wave slice: rps[w][row within 128]
        int o = w * 128 + (row_l & 127);
        rpd[o] = dsum; rpp[o] = psum; rpm[o] = msum;
      }
    }
  }

  if (!diag) {
    // col partials: shfl-combine the 4 row-groups within the wave, park in LDS
    #pragma unroll
    for (int n = 0; n < 4; n++) {
      float d = cd[n], p = cp[n], mm = cm[n];
      d += __shfl_xor(d, 16); d += __shfl_xor(d, 32);
      p += __shfl_xor(p, 16); p += __shfl_xor(p, 32);
      mm += __shfl_xor(mm, 16); mm += __shfl_xor(mm, 32);
      if (l < 16) {
        int o = ((w * 4 + n) * 16 + cl) * 3;
        cps[o] = d; cps[o + 1] = p; cps[o + 2] = mm;
      }
    }
  }
  __syncthreads();

  // row side: sum the 4 wc-wave slices, coalesced store
  if (t < 256) {
    int b0 = (t >> 7) * 512 + (t & 127);   // wr block base in rps
    float d = rpd[b0] + rpd[b0 + 128] + rpd[b0 + 256] + rpd[b0 + 384];
    float p = rpp[b0] + rpp[b0 + 128] + rpp[b0 + 256] + rpp[b0 + 384];
    float mm = rpm[b0] + rpm[b0 + 128] + rpm[b0 + 256] + rpm[b0 + 384];
    ps[t] = d; ps[256 + t] = p; ps[512 + t] = mm;
  }
  // col side: combine wr=0/wr=1 wave pairs, store (non-diag only; k_reduce
  // never reads the diag col side)
  if (!diag && wr == 0 && l < 16) {
    #pragma unroll
    for (int n = 0; n < 4; n++) {
      int o0 = ((w * 4 + n) * 16 + cl) * 3;
      int o1 = (((w + 4) * 4 + n) * 16 + cl) * 3;
      int col_l = wc * 64 + n * 16 + cl;
      ps[768 + col_l] = cps[o0] + cps[o1];
      ps[768 + 256 + col_l] = cps[o0 + 1] + cps[o1 + 1];
      ps[768 + 512 + col_l] = cps[o0 + 2] + cps[o1 + 2];
    }
  }
}

// ---- Kernel 3: reduce partials + per-row loss + per-block partial sum ----
__global__ __launch_bounds__(256) void k_reduce(
    const float* __restrict__ part, const int* __restrict__ mids,
    float* __restrict__ blockout) {
  __shared__ int hist[256];
  __shared__ float reds[256];
  __shared__ int redc[256];
  int t = threadIdx.x;
  hist[t] = 0;
  __syncthreads();
  for (int i = t; i < M_ROWS; i += 256) atomicAdd(&hist[mids[i]], 1);
  __syncthreads();

  int p = blockIdx.x;                       // panel 0..27
  int i = p * 256 + t;                      // row 0..7167
  float d = 0.f, pp = 0.f, mm = 0.f;
  int base = p * TILES2 - p * (p - 1) / 2;  // tbid(p, p)
  for (int yy = p; yy < TILES2; yy++) {     // row-side from tiles (p, yy)
    const float* s = part + (size_t)(base + yy - p) * SLOT;
    d += s[t]; pp += s[256 + t]; mm += s[512 + t];
  }
  for (int xx = 0; xx < p; xx++) {          // col-side from tiles (xx, p)
    int b = xx * TILES2 - xx * (xx - 1) / 2 + (p - xx);
    const float* s = part + (size_t)b * SLOT + 768;
    d += s[t]; pp += s[256 + t]; mm += s[512 + t];
  }

  int vmid; bool sh = false;
  if (i < TEXT_OFF) vmid = mids[i];
  else if (i < SHUF_OFF) vmid = mids[(i - TEXT_OFF) / 3];
  else { vmid = mids[(i - SHUF_OFF) / 3]; sh = true; }
  int c = hist[vmid];
  int npos = sh ? (3 * c - 1) : (4 * c - 1);
  int nneg = N_TOT - 1 - npos;
  float val = 0.f; int cnt = 0;
  if (npos > 0 && nneg > 0) {
    val = logf(d) - pp / (float)(npos > 1 ? npos : 1) + mm / (float)(nneg > 1 ? nneg : 1);
    cnt = 1;
  }
  reds[t] = val; redc[t] = cnt;
  __syncthreads();
  for (int s2 = 128; s2 > 0; s2 >>= 1) {
    if (t < s2) { reds[t] += reds[t + s2]; redc[t] += redc[t + s2]; }
    __syncthreads();
  }
  if (t == 0) { blockout[p * 2] = reds[0]; blockout[p * 2 + 1] = (float)redc[0]; }
}

// ---------------- Kernel 4: final scalar ----------------
__global__ __launch_bounds__(64) void k_final(
    const float* __restrict__ blockout, float* __restrict__ out) {
  int t = threadIdx.x;
  float s = 0.f, c = 0.f;
  if (t < TILES2) { s = blockout[t * 2]; c = blockout[t * 2 + 1]; }
  #pragma unroll
  for (int m = 32; m > 0; m >>= 1) { s += __shfl_down(s, m); c += __shfl_down(c, m); }
  if (t == 0) out[0] = (c > 0.f) ? s / c : 0.f;
}

// ---------------- Launch ----------------
extern "C" void kernel_launch(void* const* d_in, const int* in_sizes, int n_in,
                              void* d_out, int out_size, void* d_ws, size_t ws_size,
                              hipStream_t stream) {
  const float* motion = (const float*)d_in[0];
  const float* text   = (const float*)d_in[1];
  const float* shuf   = (const float*)d_in[2];
  const int*   mids   = (const int*)d_in[3];

  char* ws = (char*)d_ws;
  ushort* emb = (ushort*)ws;                                  // 7,340,032 B
  int* ids    = (int*)(ws + (size_t)N_TOT * DIM * 2);         // 28,672 B
  float* blockout = (float*)(ws + 7368704);                   // 28*2 floats
  float* part = (float*)(ws + 7454720);                       // 406*1536*4 = 2,494,464 B

  k_normalize<<<N_TOT / 4, 256, 0, stream>>>(motion, text, shuf, mids, emb, ids);
  k_gemm_loss<<<NBLK2, 512, 0, stream>>>(emb, ids, part);
  k_reduce<<<TILES2, 256, 0, stream>>>(part, mids, blockout);
  k_final<<<1, 64, 0, stream>>>(blockout, (float*)d_out);
}